// Round 8
// baseline (578.258 us; speedup 1.0000x reference)
//
#include <hip/hip_runtime.h>
#include <math.h>

// Problem constants
#define NPIX   131072      // 32*64*64 pixels
#define KCODES 512
#define DIM    64
#define HW     4096        // 64*64
#define CHW    262144      // 64*4096

// Output layout (floats, concatenated in reference return order)
#define O_Q    1ll
#define O_PERP 8388609ll
#define O_ENC  8388610ll
#define O_IDX  75497474ll

// ws layout (floats): [0] loss accum, [1..512] counts (u32), [513..1024] esq

// Replicate numpy pairwise_sum of x**2 for n=64 (8 accs, stride-8, pairwise combine).
__device__ __forceinline__ float np_sumsq64(const float (&x)[64]) {
#pragma clang fp contract(off)
  float r0 = x[0]*x[0], r1 = x[1]*x[1], r2 = x[2]*x[2], r3 = x[3]*x[3];
  float r4 = x[4]*x[4], r5 = x[5]*x[5], r6 = x[6]*x[6], r7 = x[7]*x[7];
#pragma unroll
  for (int i = 8; i < 64; i += 8) {
    r0 += x[i+0]*x[i+0];
    r1 += x[i+1]*x[i+1];
    r2 += x[i+2]*x[i+2];
    r3 += x[i+3]*x[i+3];
    r4 += x[i+4]*x[i+4];
    r5 += x[i+5]*x[i+5];
    r6 += x[i+6]*x[i+6];
    r7 += x[i+7]*x[i+7];
  }
  return ((r0+r1)+(r2+r3))+((r4+r5)+(r6+r7));
}

// Prep: zero loss accumulator + counts, compute esq[k] (np-pairwise) into ws.
__global__ void vq_prep(const float* __restrict__ emb, float* __restrict__ ws) {
  const int t = threadIdx.x;  // 512 threads
  if (t == 0) ws[0] = 0.0f;
  ((unsigned*)ws)[1 + t] = 0u;
  float x[64];
  const float* e = emb + t * DIM;
#pragma unroll
  for (int d = 0; d < 64; ++d) x[d] = e[d];
  ws[513 + t] = np_sumsq64(x);
}

// Main, round 8: LDS serves ONLY the e-operand.
// Round 7 was LDS-pipe-bound: 8px x 8codes tile = 4 ds_read_b128 per 64 fma
// -> 82us LDS demand/CU vs 55us VALU floor. New tile: thread = 16px x 4codes.
// The 16 z values per d come from WAVE-UNIFORM global float4 loads (all 64
// lanes of a wave share one px-group g = t>>7 -> broadcast, 1 L1-hot line,
// VMEM pipe); e comes from ONE ds_read_b128 per d (contiguous 1024B/wave,
// conflict-free). LDS compute demand drops 5x to ~20us/CU.
// Exactness preserved: per (px,code) single ascending-d fmaf chain,
// dist=(zsq+esq)-2*dot same rounding, thread-local ascending-k scan,
// 64-lane butterfly with (dist, lower-k) tie-break, cross-wave merge prefers
// the lower-code wave on ties => np.argmin semantics exactly.
__global__ __launch_bounds__(256)
__attribute__((amdgpu_waves_per_eu(4, 4)))
void vq_main(
    const float* __restrict__ z, const float* __restrict__ emb,
    float* __restrict__ out, float* __restrict__ ws)
{
  __shared__ float ET_s[16 * 512];   // 32KB: 16-d slice of embT: [dl][code]
  __shared__ float esq_l[512];
  __shared__ float zsq_l[32];
  __shared__ int   ridx_l[32];
  __shared__ float md[4][16];
  __shared__ int   mk[4][16];
  __shared__ float wsum[4];

  const int t   = threadIdx.x;
  const int u   = t & 127;           // code group: codes 4u..4u+3
  const int g   = t >> 7;            // px group: px 16g..16g+15 (wave-uniform)
  const int blk = blockIdx.x;        // grid = 4096
  const int n0  = blk * 32;          // 32 consecutive pixels (same batch b)
  const int b   = n0 >> 12;
  const int hw0 = n0 & 4095;
  const float* zblk = z + (size_t)b * CHW + hw0;       // block's 32-px column
  const float* zgb  = zblk + 16 * g;                    // wave's 16-px column

  esq_l[t]       = ws[513 + t];
  esq_l[t + 256] = ws[769 + t];

  // Exact per-pixel zsq (np pairwise), threads 0..31; coalesced strided reads
  // (lanes 0..31 = consecutive px -> 128B segments) that also warm L1/L2 for
  // the compute stream.
  if (t < 32) {
    float x[64];
#pragma unroll
    for (int d = 0; d < 64; ++d) x[d] = zblk[(size_t)d * HW + t];
    zsq_l[t] = np_sumsq64(x);
  }

  float acc[16][4];
#pragma unroll
  for (int j = 0; j < 16; ++j)
#pragma unroll
    for (int r = 0; r < 4; ++r) acc[j][r] = 0.0f;

  for (int s = 0; s < 4; ++s) {
    if (s) __syncthreads();          // all waves done reading previous slice
    // Stage ET_s[dl][c] = emb[c][16s+dl] for c = t and t+256.
#pragma unroll
    for (int h = 0; h < 2; ++h) {
      const int c = t + 256 * h;
      const float* er = emb + (size_t)c * 64 + 16 * s;
      const float4 v0 = *(const float4*)(er + 0);
      const float4 v1 = *(const float4*)(er + 4);
      const float4 v2 = *(const float4*)(er + 8);
      const float4 v3 = *(const float4*)(er + 12);
      float tmp[16] = {v0.x, v0.y, v0.z, v0.w, v1.x, v1.y, v1.z, v1.w,
                       v2.x, v2.y, v2.z, v2.w, v3.x, v3.y, v3.z, v3.w};
#pragma unroll
      for (int dl = 0; dl < 16; ++dl) ET_s[dl * 512 + c] = tmp[dl];
    }
    __syncthreads();

#pragma unroll 2
    for (int dl = 0; dl < 16; ++dl) {
      const int d = 16 * s + dl;
      const float* zr = zgb + (size_t)d * HW;          // wave-uniform addr
      const float4 z0 = *(const float4*)(zr + 0);
      const float4 z1 = *(const float4*)(zr + 4);
      const float4 z2 = *(const float4*)(zr + 8);
      const float4 z3 = *(const float4*)(zr + 12);
      const float4 e4 = *(const float4*)&ET_s[dl * 512 + 4 * u];
      const float zv[16] = {z0.x, z0.y, z0.z, z0.w, z1.x, z1.y, z1.z, z1.w,
                            z2.x, z2.y, z2.z, z2.w, z3.x, z3.y, z3.z, z3.w};
      const float ev[4] = {e4.x, e4.y, e4.z, e4.w};
#pragma unroll
      for (int j = 0; j < 16; ++j)
#pragma unroll
        for (int r = 0; r < 4; ++r)
          acc[j][r] = fmaf(zv[j], ev[r], acc[j][r]);
    }
  }

  // ---- per-px argmin over this thread's 4 codes (ascending k, strict <) ----
  float bd[16];
  int   bk[16];
#pragma unroll
  for (int j = 0; j < 16; ++j) {
    const float zq = zsq_l[16 * g + j];
    float best = INFINITY; int bi = 0;
#pragma unroll
    for (int r = 0; r < 4; ++r) {
      const int k = 4 * u + r;
      const float dist = (zq + esq_l[k]) - 2.0f * acc[j][r];
      if (dist < best) { best = dist; bi = k; }
    }
    bd[j] = best; bk[j] = bi;
  }
  // Butterfly over the wave's 64 lanes (covers 256 codes), tie -> lower k.
#pragma unroll
  for (int m = 32; m >= 1; m >>= 1) {
#pragma unroll
    for (int j = 0; j < 16; ++j) {
      const float od = __shfl_xor(bd[j], m, 64);
      const int   ok = __shfl_xor(bk[j], m, 64);
      if (od < bd[j] || (od == bd[j] && ok < bk[j])) { bd[j] = od; bk[j] = ok; }
    }
  }
  // Publish per-wave results; cross-wave merge (wave 2g has codes 0..255,
  // wave 2g+1 has 256..511; tie keeps the lower-code wave).
  {
    const int w = t >> 6;
    if ((t & 63) == 0) {
#pragma unroll
      for (int j = 0; j < 16; ++j) { md[w][j] = bd[j]; mk[w][j] = bk[j]; }
    }
  }
  __syncthreads();
  if (t < 32) {
    const int g2 = t >> 4, pl = t & 15;
    const float d0 = md[2 * g2][pl];     const int k0 = mk[2 * g2][pl];
    const float d1 = md[2 * g2 + 1][pl]; const int k1 = mk[2 * g2 + 1][pl];
    const int kb = (d1 < d0) ? k1 : k0;  // tie -> k0 (lower code range)
    ridx_l[t] = kb;
    out[O_IDX + n0 + t] = (float)kb;
    atomicAdd((unsigned*)ws + 1 + kb, 1u);
  }
  __syncthreads();

  // ---- epilogue: quantized (to [B,C,H,W]) + loss, all 256 threads ----
  {
    const int px = t & 31;
    const int dq = t >> 5;               // 8 d's per thread
    const int kq = ridx_l[px];
    const float* e0 = emb + ((size_t)kq << 6) + 8 * dq;
    float* q0 = out + O_Q + (size_t)b * CHW + hw0 + px;
    const float* zq = zblk + px;
    float lsum = 0.0f;
#pragma unroll
    for (int j = 0; j < 8; ++j) {
      const int d = 8 * dq + j;
      const float ev = e0[j];
      const float df = ev - zq[(size_t)d * HW];
      lsum = fmaf(df, df, lsum);
      q0[(size_t)d * HW] = ev;
    }
#pragma unroll
    for (int off = 32; off > 0; off >>= 1) lsum += __shfl_down(lsum, off, 64);
    if ((t & 63) == 0) wsum[t >> 6] = lsum;
  }
  __syncthreads();
  if (t == 0) atomicAdd(ws, (wsum[0] + wsum[1]) + (wsum[2] + wsum[3]));

  // Encodings: 32 rows x 256 float2, coalesced one-hot stores.
  float2* enc = (float2*)(out + O_ENC) + (size_t)n0 * 256;
  for (int i = t; i < 32 * 256; i += 256) {
    const int r  = i >> 8;
    const int c2 = i & 255;
    const int bv = ridx_l[r];
    float2 v = make_float2(0.0f, 0.0f);
    if ((bv >> 1) == c2) {
      if (bv & 1) v.y = 1.0f; else v.x = 1.0f;
    }
    enc[i] = v;
  }
}

// Finalize: perplexity from counts (exact: counts/2^17), loss mean.
__global__ void vq_fin(float* __restrict__ out, const float* __restrict__ ws) {
  __shared__ float red[8];
  const int t = threadIdx.x;  // 512
  const unsigned* counts = (const unsigned*)ws + 1;
  const float p = (float)counts[t] * (1.0f / 131072.0f);
  float h = p * logf(p + 1e-10f);
#pragma unroll
  for (int off = 32; off > 0; off >>= 1) h += __shfl_down(h, off, 64);
  if ((t & 63) == 0) red[t >> 6] = h;
  __syncthreads();
  if (t == 0) {
    float H = 0.0f;
#pragma unroll
    for (int w = 0; w < 8; ++w) H += red[w];
    out[O_PERP] = expf(-H);
    out[0] = 1.25f * ws[0] * (1.0f / 8388608.0f);
  }
}

extern "C" void kernel_launch(void* const* d_in, const int* in_sizes, int n_in,
                              void* d_out, int out_size, void* d_ws, size_t ws_size,
                              hipStream_t stream) {
  const float* z   = (const float*)d_in[0];
  const float* emb = (const float*)d_in[1];
  float* out = (float*)d_out;
  float* ws  = (float*)d_ws;

  vq_prep<<<1, 512, 0, stream>>>(emb, ws);
  vq_main<<<4096, 256, 0, stream>>>(z, emb, out, ws);
  vq_fin<<<1, 512, 0, stream>>>(out, ws);
}